// Round 1
// 7641.491 us; speedup vs baseline: 2.9444x; 2.9444x over previous
//
#include <hip/hip_runtime.h>
#include <cmath>

// Transformer encoder-decoder forward.
// GEMMs run as bf16x3-split MFMA (hi/lo decomposition, 3 MFMA terms) for
// near-fp32 accuracy at matrix-core rates. Attention score/PV/softmax/LN
// remain fp32 vector (next round's target).
// B=8 S=T=512 D=512 H=8 DK=64 L=6 F=2048 V=32000

#define Bz 8
#define Sz 512
#define Tz 512
#define Dz 512
#define Hz 8
#define Lz 6
#define Fz 2048
#define Vz 32000
#define DKz 64
#define NEGV (-1e9f)
#define EPSv 1e-5f

typedef unsigned short u16;
typedef unsigned int u32;
typedef __attribute__((ext_vector_type(8))) short short8;
typedef __attribute__((ext_vector_type(4))) float f32x4;

__device__ __forceinline__ u16 f2bf(float x) {
  u32 u = __builtin_bit_cast(u32, x);
  u32 r = (u + 0x7fffu + ((u >> 16) & 1u)) >> 16;  // RNE
  return (u16)r;
}
__device__ __forceinline__ float bf2f(u16 h) {
  u32 u = ((u32)h) << 16;
  return __builtin_bit_cast(float, u);
}

// ---------------- embedding + positional encoding ----------------
__global__ __launch_bounds__(256) void embed_kernel(
    const int* __restrict__ tok, const float* __restrict__ emb,
    const float* __restrict__ pos, float* __restrict__ out) {
  int row = blockIdx.x;  // b*S + s
  int s = row & (Sz - 1);
  int t = tok[row];
  const float* e = emb + (size_t)t * Dz;
  const float* p = pos + (size_t)s * Dz;
  float* o = out + (size_t)row * Dz;
  for (int c = threadIdx.x; c < Dz; c += 256) o[c] = e[c] + p[c];
}

// ---------------- split fp32 activation -> bf16 hi/lo ----------------
__global__ __launch_bounds__(256) void split_act_kernel(
    const float* __restrict__ X, u16* __restrict__ Hi, u16* __restrict__ Lo,
    int n4) {
  int stride = gridDim.x * 256;
  for (int i = blockIdx.x * 256 + threadIdx.x; i < n4; i += stride) {
    float4 v = reinterpret_cast<const float4*>(X)[i];
    float vv[4] = {v.x, v.y, v.z, v.w};
    u16 h[4], l[4];
#pragma unroll
    for (int j = 0; j < 4; ++j) {
      h[j] = f2bf(vv[j]);
      l[j] = f2bf(vv[j] - bf2f(h[j]));
    }
    uint2 H = make_uint2((u32)h[0] | ((u32)h[1] << 16),
                         (u32)h[2] | ((u32)h[3] << 16));
    uint2 L = make_uint2((u32)l[0] | ((u32)l[1] << 16),
                         (u32)l[2] | ((u32)l[3] << 16));
    reinterpret_cast<uint2*>(Hi)[i] = H;
    reinterpret_cast<uint2*>(Lo)[i] = L;
  }
}

// ---------------- split + transpose weights: W[K][N] -> WT hi/lo [N][K] ----------------
// batched over blockIdx.z (matrices contiguous with strideW / strideT)
__global__ __launch_bounds__(256) void split_wT_kernel(
    const float* __restrict__ W, u16* __restrict__ Hi, u16* __restrict__ Lo,
    int K, int ldw, long long strideW, long long strideT) {
  __shared__ float tile[32][33];
  const float* Wm = W + (size_t)blockIdx.z * strideW;
  u16* Him = Hi + (size_t)blockIdx.z * strideT;
  u16* Lom = Lo + (size_t)blockIdx.z * strideT;
  int n0 = blockIdx.x * 32, k0 = blockIdx.y * 32;
  int c = threadIdx.x & 31, r0 = threadIdx.x >> 5;
  for (int rr = r0; rr < 32; rr += 8)
    tile[rr][c] = Wm[(size_t)(k0 + rr) * ldw + n0 + c];
  __syncthreads();
  for (int rr = r0; rr < 32; rr += 8) {
    float x = tile[c][rr];  // = W[k0+c][n0+rr]
    u16 h = f2bf(x);
    size_t o = (size_t)(n0 + rr) * K + k0 + c;
    Him[o] = h;
    Lom[o] = f2bf(x - bf2f(h));
  }
}

// ---------------- bf16x3 MFMA GEMM ----------------
// C[M,N] = A[M,K] @ B[K,N] + bias  where A ~ Ahi+Alo, B given as BT hi/lo [N][K].
// 128x128 tile, BK=32, 4 waves (each wave 64x64 = 4x4 frags of 16x16x32).
// LDS panels are LINEAR (global_load_lds writes base+lane*16); bank-conflict
// avoidance via inverse-swizzled GLOBAL source + swizzled ds_read:
//   phys_slot = logical_slot ^ ((row>>1)&3)   (slots are 16B within a 64B row)
// A/B k-position mapping: row/col = lane&15, k = (lane>>4)*8 + i. Any
// consistent per-lane-group bijection of k is valid (A and B permute alike);
// C/D layout is the HW-verified col=lane&15, row=(lane>>4)*4+reg.
__device__ __forceinline__ void gload16(const u16* g, u16* l) {
  __builtin_amdgcn_global_load_lds(
      (__attribute__((address_space(1))) void*)(g),
      (__attribute__((address_space(3))) void*)(l), 16, 0, 0);
}

__global__ __launch_bounds__(256) void gemm_bf3_kernel(
    const u16* __restrict__ Ahi, const u16* __restrict__ Alo,
    const u16* __restrict__ Bhi, const u16* __restrict__ Blo,
    const float* __restrict__ bias, float* __restrict__ C,
    int M, int N, int K, int ldc, int relu) {
  (void)M; (void)N;
  __shared__ __align__(16) u16 sm[4][128 * 32];  // Ahi,Alo,Bhi,Blo panels (8KB each)
  int tid = threadIdx.x;
  int wave = tid >> 6, lane = tid & 63;
  int lr = lane & 15, lg = lane >> 4;
  int wr = wave >> 1, wc = wave & 1;
  int row0 = blockIdx.y * 128, col0 = blockIdx.x * 128;

  // staging: wave handles chunks {2w, 2w+1}; lane covers (row, 16B slot)
  size_t aoff[2], boff[2];
  u16* dst[2][4];
#pragma unroll
  for (int cc = 0; cc < 2; ++cc) {
    int c = 2 * wave + cc;
    int r = c * 16 + (lane >> 2);
    int sg = (lane & 3) ^ ((r >> 1) & 3);  // inverse swizzle on global source
    aoff[cc] = (size_t)(row0 + r) * K + sg * 8;
    boff[cc] = (size_t)(col0 + r) * K + sg * 8;
    dst[cc][0] = &sm[0][c * 512];
    dst[cc][1] = &sm[1][c * 512];
    dst[cc][2] = &sm[2][c * 512];
    dst[cc][3] = &sm[3][c * 512];
  }

  // frag ds_read offsets (u16 units), fixed per lane
  int aro[4], bro[4];
#pragma unroll
  for (int m = 0; m < 4; ++m) {
    int ra = wr * 64 + m * 16 + lr;
    aro[m] = ra * 32 + ((lg ^ ((ra >> 1) & 3)) * 8);
    int rb = wc * 64 + m * 16 + lr;
    bro[m] = rb * 32 + ((lg ^ ((rb >> 1) & 3)) * 8);
  }

  const f32x4 zero = {0.f, 0.f, 0.f, 0.f};
  f32x4 acc[4][4];
#pragma unroll
  for (int m = 0; m < 4; ++m)
#pragma unroll
    for (int n = 0; n < 4; ++n) acc[m][n] = zero;

  for (int k0 = 0; k0 < K; k0 += 32) {
#pragma unroll
    for (int cc = 0; cc < 2; ++cc) {
      gload16(Ahi + aoff[cc] + k0, dst[cc][0]);
      gload16(Alo + aoff[cc] + k0, dst[cc][1]);
      gload16(Bhi + boff[cc] + k0, dst[cc][2]);
      gload16(Blo + boff[cc] + k0, dst[cc][3]);
    }
    __syncthreads();  // drains vmcnt before barrier (compiler-inserted)
    short8 ahf[4], alf[4];
#pragma unroll
    for (int m = 0; m < 4; ++m) {
      ahf[m] = *reinterpret_cast<const short8*>(&sm[0][aro[m]]);
      alf[m] = *reinterpret_cast<const short8*>(&sm[1][aro[m]]);
    }
#pragma unroll
    for (int n = 0; n < 4; ++n) {
      short8 bhf = *reinterpret_cast<const short8*>(&sm[2][bro[n]]);
      short8 blf = *reinterpret_cast<const short8*>(&sm[3][bro[n]]);
#pragma unroll
      for (int m = 0; m < 4; ++m) {
        acc[m][n] = __builtin_amdgcn_mfma_f32_16x16x32_bf16(ahf[m], bhf, acc[m][n], 0, 0, 0);
        acc[m][n] = __builtin_amdgcn_mfma_f32_16x16x32_bf16(alf[m], bhf, acc[m][n], 0, 0, 0);
        acc[m][n] = __builtin_amdgcn_mfma_f32_16x16x32_bf16(ahf[m], blf, acc[m][n], 0, 0, 0);
      }
    }
    __syncthreads();
  }

#pragma unroll
  for (int n = 0; n < 4; ++n) {
    int col = col0 + wc * 64 + n * 16 + lr;
    float bv = bias[col];
#pragma unroll
    for (int m = 0; m < 4; ++m) {
#pragma unroll
      for (int j = 0; j < 4; ++j) {
        int row = row0 + wr * 64 + m * 16 + lg * 4 + j;
        float v = acc[m][n][j] + bv;
        if (relu) v = fmaxf(v, 0.0f);
        C[(size_t)row * ldc + col] = v;
      }
    }
  }
}

// ---------------- attention scores: Sc[bh,q,k] = (Q.K^T)/8, masked ----------------
__global__ __launch_bounds__(256) void attn_scores_kernel(
    const float* __restrict__ Q, const float* __restrict__ Kp,
    const int* __restrict__ tok, float* __restrict__ Sc, int mask_type,
    int ldq, int ldk) {
  __shared__ float Qs[64][DKz + 1];
  __shared__ float Ks[64][DKz + 1];
  int bh = blockIdx.z;
  int b = bh >> 3, h = bh & 7;
  int q0 = blockIdx.y * 64, k0 = blockIdx.x * 64;
  int tid = threadIdx.x;
  size_t qbase = ((size_t)b * Sz + q0) * ldq + h * DKz;
  size_t kbase = ((size_t)b * Sz + k0) * ldk + h * DKz;
  for (int i = tid; i < 64 * 64; i += 256) {
    int r = i >> 6, c = i & 63;
    Qs[r][c] = Q[qbase + (size_t)r * ldq + c];
    Ks[r][c] = Kp[kbase + (size_t)r * ldk + c];
  }
  __syncthreads();
  int tx = tid & 15, ty = tid >> 4;
  float acc[4][4] = {};
#pragma unroll 4
  for (int kk = 0; kk < DKz; ++kk) {
    float a[4], b4[4];
#pragma unroll
    for (int i = 0; i < 4; ++i) a[i] = Qs[ty * 4 + i][kk];
#pragma unroll
    for (int j = 0; j < 4; ++j) b4[j] = Ks[tx * 4 + j][kk];
#pragma unroll
    for (int i = 0; i < 4; ++i)
#pragma unroll
      for (int j = 0; j < 4; ++j) acc[i][j] += a[i] * b4[j];
  }
  const float scale = 0.125f;  // 1/sqrt(64)
#pragma unroll
  for (int i = 0; i < 4; ++i) {
    int q = q0 + ty * 4 + i;
    bool qvalid = (mask_type == 2) ? (tok[b * Tz + q] != 0) : true;
#pragma unroll
    for (int j = 0; j < 4; ++j) {
      int k = k0 + tx * 4 + j;
      bool valid = (mask_type == 1) ? (tok[b * Sz + k] != 0) : (qvalid && (k <= q));
      Sc[((size_t)bh * Sz + q) * Sz + k] = valid ? acc[i][j] * scale : NEGV;
    }
  }
}

// ---------------- softmax over last dim (rows of length 512) ----------------
__global__ __launch_bounds__(256) void softmax_kernel(float* __restrict__ Sc) {
  __shared__ float red[256];
  size_t row = blockIdx.x;
  float* p = Sc + row * Sz;
  int tid = threadIdx.x;
  float v0 = p[tid], v1 = p[tid + 256];
  red[tid] = fmaxf(v0, v1);
  __syncthreads();
  for (int s = 128; s > 0; s >>= 1) {
    if (tid < s) red[tid] = fmaxf(red[tid], red[tid + s]);
    __syncthreads();
  }
  float m = red[0];
  __syncthreads();
  float e0 = expf(v0 - m), e1 = expf(v1 - m);
  red[tid] = e0 + e1;
  __syncthreads();
  for (int s = 128; s > 0; s >>= 1) {
    if (tid < s) red[tid] += red[tid + s];
    __syncthreads();
  }
  float inv = 1.0f / red[0];
  p[tid] = e0 * inv;
  p[tid + 256] = e1 * inv;
}

// ---------------- PV: O[b,q,h*64+d] = sum_k P[bh,q,k] * V[b,k,:] ----------------
__global__ __launch_bounds__(256) void attn_pv_kernel(
    const float* __restrict__ P, const float* __restrict__ V,
    float* __restrict__ O, int ldv) {
  __shared__ float Ps[64][32 + 1];
  __shared__ float Vs[32][64 + 1];
  int bh = blockIdx.y;
  int b = bh >> 3, h = bh & 7;
  int q0 = blockIdx.x * 64;
  int tid = threadIdx.x;
  int tx = tid & 15, ty = tid >> 4;
  float acc[4][4] = {};
  for (int k0 = 0; k0 < Sz; k0 += 32) {
    for (int i = tid; i < 64 * 32; i += 256) {
      int r = i >> 5, c = i & 31;
      Ps[r][c] = P[((size_t)bh * Sz + q0 + r) * Sz + k0 + c];
    }
    for (int i = tid; i < 32 * 64; i += 256) {
      int r = i >> 6, c = i & 63;
      Vs[r][c] = V[((size_t)(b * Sz + k0 + r)) * ldv + h * DKz + c];
    }
    __syncthreads();
#pragma unroll 4
    for (int kk = 0; kk < 32; ++kk) {
      float a[4], b4[4];
#pragma unroll
      for (int i = 0; i < 4; ++i) a[i] = Ps[ty * 4 + i][kk];
#pragma unroll
      for (int j = 0; j < 4; ++j) b4[j] = Vs[kk][tx * 4 + j];
#pragma unroll
      for (int i = 0; i < 4; ++i)
#pragma unroll
        for (int j = 0; j < 4; ++j) acc[i][j] += a[i] * b4[j];
    }
    __syncthreads();
  }
#pragma unroll
  for (int i = 0; i < 4; ++i)
#pragma unroll
    for (int j = 0; j < 4; ++j)
      O[((size_t)(b * Sz + q0 + ty * 4 + i)) * Dz + h * DKz + tx * 4 + j] = acc[i][j];
}

// ---------------- fused residual + LayerNorm ----------------
__global__ __launch_bounds__(256) void ln_kernel(
    const float* __restrict__ X, const float* __restrict__ Aa,
    const float* __restrict__ g, const float* __restrict__ bb,
    float* __restrict__ Out) {
  __shared__ float red[256];
  size_t row = blockIdx.x;
  int tid = threadIdx.x;
  float v0 = X[row * Dz + tid] + Aa[row * Dz + tid];
  float v1 = X[row * Dz + tid + 256] + Aa[row * Dz + tid + 256];
  red[tid] = v0 + v1;
  __syncthreads();
  for (int s = 128; s > 0; s >>= 1) {
    if (tid < s) red[tid] += red[tid + s];
    __syncthreads();
  }
  float mu = red[0] * (1.0f / Dz);
  __syncthreads();
  float d0 = v0 - mu, d1 = v1 - mu;
  red[tid] = d0 * d0 + d1 * d1;
  __syncthreads();
  for (int s = 128; s > 0; s >>= 1) {
    if (tid < s) red[tid] += red[tid + s];
    __syncthreads();
  }
  float rstd = rsqrtf(red[0] * (1.0f / Dz) + EPSv);
  Out[row * Dz + tid] = d0 * rstd * g[tid] + bb[tid];
  Out[row * Dz + tid + 256] = d1 * rstd * g[tid + 256] + bb[tid + 256];
}

extern "C" void kernel_launch(void* const* d_in, const int* in_sizes, int n_in,
                              void* d_out, int out_size, void* d_ws, size_t ws_size,
                              hipStream_t stream) {
  const int*   src       = (const int*)d_in[0];
  const int*   tgt       = (const int*)d_in[1];
  const float* enc_emb   = (const float*)d_in[2];
  const float* dec_emb   = (const float*)d_in[3];
  const float* pos_enc   = (const float*)d_in[4];
  const float* enc_attn_w = (const float*)d_in[5];
  const float* enc_attn_b = (const float*)d_in[6];
  const float* enc_ff_w1 = (const float*)d_in[7];
  const float* enc_ff_b1 = (const float*)d_in[8];
  const float* enc_ff_w2 = (const float*)d_in[9];
  const float* enc_ff_b2 = (const float*)d_in[10];
  const float* enc_ln_g  = (const float*)d_in[11];
  const float* enc_ln_b  = (const float*)d_in[12];
  const float* dec_attn_w = (const float*)d_in[13];
  const float* dec_attn_b = (const float*)d_in[14];
  const float* dec_ff_w1 = (const float*)d_in[15];
  const float* dec_ff_b1 = (const float*)d_in[16];
  const float* dec_ff_w2 = (const float*)d_in[17];
  const float* dec_ff_b2 = (const float*)d_in[18];
  const float* dec_ln_g  = (const float*)d_in[19];
  const float* dec_ln_b  = (const float*)d_in[20];
  const float* fc_w      = (const float*)d_in[21];
  const float* fc_b      = (const float*)d_in[22];
  float* out = (float*)d_out;

  const size_t BSD = (size_t)Bz * Sz * Dz;  // 2,097,152
  const int BS = Bz * Sz;                   // 4096 rows
  const size_t DD = (size_t)Dz * Dz;

  float* ws  = (float*)d_ws;
  float* x   = ws;                          // [BS][D] encoder activations -> enc_out
  float* y   = x + BSD;                     // [BS][D] decoder activations
  float* qkv = y + BSD;                     // [BS][1536] fused q|k|v (self) / kv+q (cross)
  float* ab  = qkv + (size_t)BS * 1536;     // [BS][D] attention output
  float* tb  = ab + BSD;                    // [BS][D] sublayer temp
  float* ffn = tb + BSD;                    // [BS][F]
  float* sc  = ffn + (size_t)BS * Fz;       // [B*H][S][S]
  u16* ahi = (u16*)(sc + (size_t)Bz * Hz * Sz * Sz);  // act split, max BS*F
  u16* alo = ahi + (size_t)BS * Fz;
  u16* whi = alo + (size_t)BS * Fz;         // weight split-T, max 16000*512
  u16* wlo = whi + (size_t)16000 * 512;
  u16* xhi = wlo + (size_t)16000 * 512;     // enc_out split (cross-attn K/V input)
  u16* xlo = xhi + BSD;

  dim3 blk(256);

  auto splitA = [&](const float* X, size_t nelem) {
    int n4 = (int)(nelem / 4);
    int grid = (n4 + 255) / 256;
    if (grid > 4096) grid = 4096;
    hipLaunchKernelGGL(split_act_kernel, dim3(grid), blk, 0, stream, X, ahi, alo, n4);
  };
  auto splitW = [&](const float* W, int K, int Ncols, int ldw, int nmat) {
    hipLaunchKernelGGL(split_wT_kernel, dim3(Ncols / 32, K / 32, nmat), blk, 0,
                       stream, W, whi, wlo, K, ldw,
                       (long long)K * Ncols, (long long)K * Ncols);
  };
  auto gemmX = [&](const u16* Ah, const u16* Al, const u16* Bh, const u16* Bl,
                   const float* bias, float* Cc, int N, int K, int ldc, int relu) {
    hipLaunchKernelGGL(gemm_bf3_kernel, dim3(N / 128, BS / 128), blk, 0, stream,
                       Ah, Al, Bh, Bl, bias, Cc, BS, N, K, ldc, relu);
  };
  auto attn = [&](const float* q, int ldq, const float* k, int ldk,
                  const float* v, int ldv, const int* tok, int mask_type,
                  float* o) {
    hipLaunchKernelGGL(attn_scores_kernel, dim3(8, 8, Bz * Hz), blk, 0, stream,
                       q, k, tok, sc, mask_type, ldq, ldk);
    hipLaunchKernelGGL(softmax_kernel, dim3(Bz * Hz * Sz), blk, 0, stream, sc);
    hipLaunchKernelGGL(attn_pv_kernel, dim3(8, Bz * Hz), blk, 0, stream, sc, v, o, ldv);
  };
  auto ln = [&](const float* X, const float* A, const float* g, const float* b,
                float* O) {
    hipLaunchKernelGGL(ln_kernel, dim3(BS), blk, 0, stream, X, A, g, b, O);
  };

  // ---------------- encoder ----------------
  hipLaunchKernelGGL(embed_kernel, dim3(BS), blk, 0, stream, src, enc_emb, pos_enc, x);
  for (int l = 0; l < Lz; ++l) {
    const float* W  = enc_attn_w + (size_t)l * 4 * DD;
    const float* Bi = enc_attn_b + (size_t)l * 4 * Dz;
    splitW(W, Dz, Dz, Dz, 4);                       // whi/wlo = [4][D][D]T
    splitA(x, BSD);
    gemmX(ahi, alo, whi, wlo, Bi, qkv, 1536, Dz, 1536, 0);  // fused q|k|v
    attn(qkv, 1536, qkv + 512, 1536, qkv + 1024, 1536, src, 1, ab);
    splitA(ab, BSD);
    gemmX(ahi, alo, whi + 3 * DD, wlo + 3 * DD, Bi + 3 * Dz, tb, Dz, Dz, Dz, 0);
    ln(x, tb, enc_ln_g + (size_t)(l * 2 + 0) * Dz, enc_ln_b + (size_t)(l * 2 + 0) * Dz, x);
    splitA(x, BSD);
    splitW(enc_ff_w1 + (size_t)l * Dz * Fz, Dz, Fz, Fz, 1);
    gemmX(ahi, alo, whi, wlo, enc_ff_b1 + (size_t)l * Fz, ffn, Fz, Dz, Fz, 1);
    splitA(ffn, (size_t)BS * Fz);
    splitW(enc_ff_w2 + (size_t)l * Fz * Dz, Fz, Dz, Dz, 1);
    gemmX(ahi, alo, whi, wlo, enc_ff_b2 + (size_t)l * Dz, tb, Dz, Fz, Dz, 0);
    ln(x, tb, enc_ln_g + (size_t)(l * 2 + 1) * Dz, enc_ln_b + (size_t)(l * 2 + 1) * Dz, x);
  }

  // enc_out split once for all cross-attention K/V projections
  {
    int n4 = (int)(BSD / 4);
    hipLaunchKernelGGL(split_act_kernel, dim3(2048), blk, 0, stream, x, xhi, xlo, n4);
  }

  // ---------------- decoder ----------------
  hipLaunchKernelGGL(embed_kernel, dim3(BS), blk, 0, stream, tgt, dec_emb, pos_enc, y);
  for (int l = 0; l < Lz; ++l) {
    const float* W  = dec_attn_w + (size_t)l * 8 * DD;
    const float* Bi = dec_attn_b + (size_t)l * 8 * Dz;
    splitW(W, Dz, Dz, Dz, 8);                       // whi/wlo = [8][D][D]T
    // self-attention (causal)
    splitA(y, BSD);
    gemmX(ahi, alo, whi, wlo, Bi, qkv, 1536, Dz, 1536, 0);
    attn(qkv, 1536, qkv + 512, 1536, qkv + 1024, 1536, tgt, 2, ab);
    splitA(ab, BSD);
    gemmX(ahi, alo, whi + 3 * DD, wlo + 3 * DD, Bi + 3 * Dz, tb, Dz, Dz, Dz, 0);
    ln(y, tb, dec_ln_g + (size_t)(l * 3 + 0) * Dz, dec_ln_b + (size_t)(l * 3 + 0) * Dz, y);
    // cross-attention: q from y, k/v from enc_out (xhi/xlo)
    splitA(y, BSD);
    float* cq = qkv + (size_t)BS * 1024;            // [BS][512] query region
    gemmX(ahi, alo, whi + 4 * DD, wlo + 4 * DD, Bi + 4 * Dz, cq, Dz, Dz, Dz, 0);
    gemmX(xhi, xlo, whi + 5 * DD, wlo + 5 * DD, Bi + 5 * Dz, qkv, 1024, Dz, 1024, 0);
    attn(cq, Dz, qkv, 1024, qkv + 512, 1024, src, 1, ab);
    splitA(ab, BSD);
    gemmX(ahi, alo, whi + 7 * DD, wlo + 7 * DD, Bi + 7 * Dz, tb, Dz, Dz, Dz, 0);
    ln(y, tb, dec_ln_g + (size_t)(l * 3 + 1) * Dz, dec_ln_b + (size_t)(l * 3 + 1) * Dz, y);
    // FFN
    splitA(y, BSD);
    splitW(dec_ff_w1 + (size_t)l * Dz * Fz, Dz, Fz, Fz, 1);
    gemmX(ahi, alo, whi, wlo, dec_ff_b1 + (size_t)l * Fz, ffn, Fz, Dz, Fz, 1);
    splitA(ffn, (size_t)BS * Fz);
    splitW(dec_ff_w2 + (size_t)l * Fz * Dz, Fz, Dz, Dz, 1);
    gemmX(ahi, alo, whi, wlo, dec_ff_b2 + (size_t)l * Dz, tb, Dz, Fz, Dz, 0);
    ln(y, tb, dec_ln_g + (size_t)(l * 3 + 2) * Dz, dec_ln_b + (size_t)(l * 3 + 2) * Dz, y);
  }

  // ---------------- final projection to vocab (2 chunks of N=16000) ----------------
  splitA(y, BSD);
  for (int c = 0; c < 2; ++c) {
    splitW(fc_w + c * 16000, Dz, 16000, Vz, 1);
    gemmX(ahi, alo, whi, wlo, fc_b + c * 16000, out + c * 16000, 16000, Dz, Vz, 0);
  }
}